// Round 12
// baseline (982.181 us; speedup 1.0000x reference)
//
#include <hip/hip_runtime.h>
#include <hip/hip_fp16.h>

typedef unsigned short u16;
typedef unsigned int   u32;

#define B_TOTAL 4096
#define NU      128
#define NS      64
#define NM      32
#define UNFOLDS 6
#define LOG2E   1.44269504088896340736f

__device__ __forceinline__ float bf2f(u16 v) {
  return __uint_as_float(((u32)v) << 16);
}
__device__ __forceinline__ u16 f2bf(float f) {  // RNE f32 -> bf16
  u32 x = __float_as_uint(f);
  return (u16)((x + 0x7fffu + ((x >> 16) & 1u)) >> 16);
}

template<bool BF16>
__device__ __forceinline__ float LD(const void* p, int i) {
  if (BF16) return bf2f(((const u16*)p)[i]);
  return ((const float*)p)[i];
}

__device__ __forceinline__ float rdlane(float v, int lane) {
  return __int_as_float(__builtin_amdgcn_readlane(__float_as_int(v), lane));
}

__device__ __forceinline__ u32 pk(float a, float b) {  // (low=a, high=b) fp16 pair
  __half2 h = __halves2half2(__float2half_rn(a), __float2half_rn(b));
  return __builtin_bit_cast(u32, h);
}
__device__ __forceinline__ float lo2f(u32 h) {
  return __low2float(__builtin_bit_cast(__half2, h));
}
__device__ __forceinline__ float hi2f(u32 h) {
  return __high2float(__builtin_bit_cast(__half2, h));
}

// Split-pipe dual-row step (unchanged from R11, proven):
//   u1 sigmoids -> trans pipe, rcp paired across rows a/b
//   u0 sigmoids -> 4096-entry LDS sigmoid table (err ~7e-4)
__device__ __forceinline__ void step2t(uint4 a, float va, float vb,
                                       const float* __restrict__ sigTab,
                                       float& na0, float& da0, float& na1, float& da1,
                                       float& nb0, float& db0, float& nb1, float& db1) {
  // ---- u1: hw trans, paired rcp across rows ----
  float ta = fmaf(va, lo2f(a.y), hi2f(a.y));
  float tb = fmaf(vb, lo2f(a.y), hi2f(a.y));
  float ea = __builtin_amdgcn_exp2f(ta);
  float eb = __builtin_amdgcn_exp2f(tb);
  float pa = 1.0f + ea, pb = 1.0f + eb;
  float rr = __builtin_amdgcn_rcpf(pa * pb);
  float sa = pb * rr, sb = pa * rr;
  na1 = fmaf(sa, hi2f(a.z), na1);  da1 = fmaf(sa, hi2f(a.w), da1);
  nb1 = fmaf(sb, hi2f(a.z), nb1);  db1 = fmaf(sb, hi2f(a.w), db1);
  // ---- u0: LDS table lookup (no trans) ----
  float t0a = fmaf(va, lo2f(a.x), hi2f(a.x));
  float t0b = fmaf(vb, lo2f(a.x), hi2f(a.x));
  float fa = __builtin_amdgcn_fmed3f(fmaf(t0a, 128.0f, 2048.5f), 0.0f, 4095.0f);
  float fb = __builtin_amdgcn_fmed3f(fmaf(t0b, 128.0f, 2048.5f), 0.0f, 4095.0f);
  float s0a = sigTab[(u32)fa];
  float s0b = sigTab[(u32)fb];
  na0 = fmaf(s0a, lo2f(a.z), na0);  da0 = fmaf(s0a, lo2f(a.w), da0);
  nb0 = fmaf(s0b, lo2f(a.z), nb0);  db0 = fmaf(s0b, lo2f(a.w), db0);
}

// 64 steps with an explicit register double-buffer: records for batch i+1
// prefetched into VGPRs while batch i computes. Breaks the per-step
// ds_read(record) -> ds_read(table) latency chain that serializes DS+VALU.
__device__ __forceinline__ void run64(const uint4* __restrict__ pR, int base,
                                      float vsa, float vsb,
                                      const float* __restrict__ sigTab,
                                      float& na0, float& da0, float& na1, float& da1,
                                      float& nb0, float& db0, float& nb1, float& db1) {
  uint4 buf[8];
  #pragma unroll
  for (int k = 0; k < 8; ++k) buf[k] = pR[(base + k) * 64];
  #pragma unroll
  for (int jb = 0; jb < 64; jb += 8) {
    uint4 nxt[8];
    #pragma unroll
    for (int k = 0; k < 8; ++k)
      nxt[k] = (jb + 8 < 64) ? pR[(base + jb + 8 + k) * 64] : buf[k];
    #pragma unroll
    for (int k = 0; k < 8; ++k) {
      float vja = rdlane(vsa, jb + k);
      float vjb = rdlane(vsb, jb + k);
      step2t(buf[k], vja, vjb, sigTab, na0, da0, na1, da1, nb0, db0, nb1, db1);
    }
    #pragma unroll
    for (int k = 0; k < 8; ++k) buf[k] = nxt[k];
  }
}

template<bool BF16>
__device__ __forceinline__ void body(
    const void* g_in, const void* g_state, const void* g_gleak, const void* g_vleak,
    const void* g_cm, const void* g_sigma, const void* g_mu, const void* g_w,
    const void* g_erev, const void* g_ssig, const void* g_smu, const void* g_sw,
    const void* g_serev, const void* g_mask, const void* g_smask,
    const void* g_iw, const void* g_ib, const void* g_ow, const void* g_ob,
    void* g_out,
    uint4* smR, float* sigTab)
{
  const int tid = threadIdx.x;           // 512 threads = 8 waves
  const int b0  = blockIdx.x * 16;       // 16 rows per block

  const int r  = tid >> 6;               // wave id, owns rows 2r, 2r+1
  const int u0 = tid & 63;
  const int u1 = u0 + 64;
  const int ba = b0 + 2 * r;
  const int bb = ba + 1;

  // ---- build sigmoid table (16 KB): s(t)=1/(1+2^t), t=(i-2048)/128 ----
  for (int i = tid; i < 4096; i += 512) {
    float t = (float)(i - 2048) * (1.0f / 128.0f);
    sigTab[i] = __builtin_amdgcn_rcpf(1.0f + __builtin_amdgcn_exp2f(t));
  }

  // ---- phase 1: stage sensory table (64 KB) ----
  #pragma unroll 2
  for (int e = tid; e < NS * 64; e += 512) {
    int s = e >> 6, l = e & 63;
    int i0 = s * NU + l, i1 = i0 + 64;
    float sl0 = LD<BF16>(g_ssig, i0) * LOG2E, sl1 = LD<BF16>(g_ssig, i1) * LOG2E;
    float ms0 = LD<BF16>(g_smu, i0) * sl0,    ms1 = LD<BF16>(g_smu, i1) * sl1;
    float w0 = LD<BF16>(g_sw, i0) * LD<BF16>(g_smask, i0) * LD<BF16>(g_serev, i0);
    float w1 = LD<BF16>(g_sw, i1) * LD<BF16>(g_smask, i1) * LD<BF16>(g_serev, i1);
    smR[e] = make_uint4(pk(-sl0, ms0), pk(-sl1, ms1), pk(w0, w1),
                        pk(fabsf(w0), fabsf(w1)));
  }
  __syncthreads();   // table + sensory staged

  // per-lane x for both rows (lane doubles as sensory index s)
  float iw = LD<BF16>(g_iw, u0), ib = LD<BF16>(g_ib, u0);
  float xa = LD<BF16>(g_in, ba * NS + u0) * iw + ib;
  float xb = LD<BF16>(g_in, bb * NS + u0) * iw + ib;
  float va0 = LD<BF16>(g_state, ba * NU + u0);
  float va1 = LD<BF16>(g_state, ba * NU + u1);
  float vb0 = LD<BF16>(g_state, bb * NU + u0);
  float vb1 = LD<BF16>(g_state, bb * NU + u1);
  const float gl0 = LD<BF16>(g_gleak, u0), gl1 = LD<BF16>(g_gleak, u1);
  const float lk0 = gl0 * LD<BF16>(g_vleak, u0);
  const float lk1 = gl1 * LD<BF16>(g_vleak, u1);
  const float cm0 = LD<BF16>(g_cm, u0) * (float)UNFOLDS;
  const float cm1 = LD<BF16>(g_cm, u1) * (float)UNFOLDS;

  const uint4* pR = smR + u0;

  // ---- sensory accumulators (once per row-pair) ----
  float nsa0 = 0.f, dsa0 = 0.f, nsa1 = 0.f, dsa1 = 0.f;
  float nsb0 = 0.f, dsb0 = 0.f, nsb1 = 0.f, dsb1 = 0.f;
  run64(pR, 0, xa, xb, sigTab,
        nsa0, dsa0, nsa1, dsa1, nsb0, dsb0, nsb1, dsb1);
  __syncthreads();   // all waves done reading sensory area

  // ---- phase 2: stage recurrent table (128 KB) over the same region ----
  #pragma unroll 4
  for (int e = tid; e < NU * 64; e += 512) {
    int j = e >> 6, l = e & 63;
    int i0 = j * NU + l, i1 = i0 + 64;
    float sl0 = LD<BF16>(g_sigma, i0) * LOG2E, sl1 = LD<BF16>(g_sigma, i1) * LOG2E;
    float ms0 = LD<BF16>(g_mu, i0) * sl0,      ms1 = LD<BF16>(g_mu, i1) * sl1;
    float w0 = LD<BF16>(g_w, i0) * LD<BF16>(g_mask, i0) * LD<BF16>(g_erev, i0);
    float w1 = LD<BF16>(g_w, i1) * LD<BF16>(g_mask, i1) * LD<BF16>(g_erev, i1);
    smR[e] = make_uint4(pk(-sl0, ms0), pk(-sl1, ms1), pk(w0, w1),
                        pk(fabsf(w0), fabsf(w1)));
  }
  __syncthreads();

  // ---- ODE unfolds: v in registers, broadcast via v_readlane; no barriers ----
  #pragma unroll 1
  for (int it = 0; it < UNFOLDS; ++it) {
    float na0 = nsa0, da0 = dsa0, na1 = nsa1, da1 = dsa1;
    float nb0 = nsb0, db0 = dsb0, nb1 = nsb1, db1 = dsb1;
    run64(pR, 0, va0, vb0, sigTab,
          na0, da0, na1, da1, nb0, db0, nb1, db1);
    run64(pR, 64, va1, vb1, sigTab,
          na0, da0, na1, da1, nb0, db0, nb1, db1);
    va0 = fmaf(cm0, va0, lk0 + na0) * __builtin_amdgcn_rcpf(cm0 + gl0 + da0 + 1e-8f);
    va1 = fmaf(cm1, va1, lk1 + na1) * __builtin_amdgcn_rcpf(cm1 + gl1 + da1 + 1e-8f);
    vb0 = fmaf(cm0, vb0, lk0 + nb0) * __builtin_amdgcn_rcpf(cm0 + gl0 + db0 + 1e-8f);
    vb1 = fmaf(cm1, vb1, lk1 + nb1) * __builtin_amdgcn_rcpf(cm1 + gl1 + db1 + 1e-8f);
  }

  // ---- epilogue: out[B,M] then v[B,U], dtype matches input ----
  if (BF16) {
    u16* om = (u16*)g_out;
    u16* ov = om + B_TOTAL * NM;
    ov[ba * NU + u0] = f2bf(va0);
    ov[ba * NU + u1] = f2bf(va1);
    ov[bb * NU + u0] = f2bf(vb0);
    ov[bb * NU + u1] = f2bf(vb1);
    if (u0 < NM) {
      float ow = LD<true>(g_ow, u0), ob = LD<true>(g_ob, u0);
      om[ba * NM + u0] = f2bf(fmaf(va0, ow, ob));
      om[bb * NM + u0] = f2bf(fmaf(vb0, ow, ob));
    }
  } else {
    float* om = (float*)g_out;
    float* ov = om + B_TOTAL * NM;
    ov[ba * NU + u0] = va0;
    ov[ba * NU + u1] = va1;
    ov[bb * NU + u0] = vb0;
    ov[bb * NU + u1] = vb1;
    if (u0 < NM) {
      float ow = LD<false>(g_ow, u0), ob = LD<false>(g_ob, u0);
      om[ba * NM + u0] = fmaf(va0, ow, ob);
      om[bb * NM + u0] = fmaf(vb0, ow, ob);
    }
  }
}

__global__ __launch_bounds__(512, 2) void ltc_kernel(
    const void* g_in, const void* g_state, const void* g_gleak, const void* g_vleak,
    const void* g_cm, const void* g_sigma, const void* g_mu, const void* g_w,
    const void* g_erev, const void* g_ssig, const void* g_smu, const void* g_sw,
    const void* g_serev, const void* g_mask, const void* g_smask,
    const void* g_iw, const void* g_ib, const void* g_ow, const void* g_ob,
    void* g_out)
{
  // LDS: 128 KB records (overlaid sensory/recurrent) + 16 KB sigmoid table
  __shared__ uint4 smR[NU * 64];
  __shared__ float sigTab[4096];

  // runtime dtype probe: sigma in [3,8]; bf16 -> even u16s decode in-range
  const u16* sg = (const u16*)g_sigma;
  int cnt = 0;
  #pragma unroll
  for (int i = 0; i < 32; ++i) {
    float f = bf2f(sg[2 * i]);
    cnt += (f >= 2.0f && f <= 16.0f) ? 1 : 0;
  }
  if (cnt >= 24)
    body<true >(g_in, g_state, g_gleak, g_vleak, g_cm, g_sigma, g_mu, g_w, g_erev,
                g_ssig, g_smu, g_sw, g_serev, g_mask, g_smask,
                g_iw, g_ib, g_ow, g_ob, g_out, smR, sigTab);
  else
    body<false>(g_in, g_state, g_gleak, g_vleak, g_cm, g_sigma, g_mu, g_w, g_erev,
                g_ssig, g_smu, g_sw, g_serev, g_mask, g_smask,
                g_iw, g_ib, g_ow, g_ob, g_out, smR, sigTab);
}

extern "C" void kernel_launch(void* const* d_in, const int* in_sizes, int n_in,
                              void* d_out, int out_size, void* d_ws, size_t ws_size,
                              hipStream_t stream) {
  (void)in_sizes; (void)n_in; (void)out_size; (void)d_ws; (void)ws_size;
  dim3 grid(B_TOTAL / 16);   // 256 blocks = 1 per CU
  dim3 block(512);           // 8 waves x 2 rows = 16 rows
  hipLaunchKernelGGL(ltc_kernel, grid, block, 0, stream,
                     d_in[0], d_in[1], d_in[2], d_in[3], d_in[4],
                     d_in[5], d_in[6], d_in[7], d_in[8],
                     d_in[9], d_in[10], d_in[11], d_in[12],
                     d_in[13], d_in[14], d_in[15], d_in[16],
                     d_in[17], d_in[18], d_out);
}

// Round 13
// 212.646 us; speedup vs baseline: 4.6188x; 4.6188x over previous
//
#include <hip/hip_runtime.h>
#include <hip/hip_fp16.h>

typedef unsigned short u16;
typedef unsigned int   u32;

#define B_TOTAL 4096
#define NU      128
#define NS      64
#define NM      32
#define UNFOLDS 6
#define LOG2E   1.44269504088896340736f

__device__ __forceinline__ float bf2f(u16 v) {
  return __uint_as_float(((u32)v) << 16);
}
__device__ __forceinline__ u16 f2bf(float f) {  // RNE f32 -> bf16
  u32 x = __float_as_uint(f);
  return (u16)((x + 0x7fffu + ((x >> 16) & 1u)) >> 16);
}

template<bool BF16>
__device__ __forceinline__ float LD(const void* p, int i) {
  if (BF16) return bf2f(((const u16*)p)[i]);
  return ((const float*)p)[i];
}

__device__ __forceinline__ float rdlane(float v, int lane) {
  return __int_as_float(__builtin_amdgcn_readlane(__float_as_int(v), lane));
}

__device__ __forceinline__ u32 pk(float a, float b) {  // (low=a, high=b) fp16 pair
  __half2 h = __halves2half2(__float2half_rn(a), __float2half_rn(b));
  return __builtin_bit_cast(u32, h);
}
__device__ __forceinline__ float lo2f(u32 h) {
  return __low2float(__builtin_bit_cast(__half2, h));
}
__device__ __forceinline__ float hi2f(u32 h) {
  return __high2float(__builtin_bit_cast(__half2, h));
}

// Granule record: TWO j-steps packed in 32 B (16-aligned) so the read is
// one ds_read_b128 + one ds_read_b64 (10 DS cyc/step vs 12 for 16B/step).
// d[0]=nsl0|msl0 (step p), d[1]=nsl1|msl1 (p), d[2]=w01 (p),
// d[3]=nsl0|msl0 (q), d[4]=nsl1|msl1 (q), d[5]=w01 (q), d[6..7]=pad
struct __align__(16) Gr { u32 d[6]; u32 pad[2]; };

__device__ __forceinline__ float tab_sig(const float* __restrict__ sigTab, float t) {
  float f = __builtin_amdgcn_fmed3f(fmaf(t, 128.0f, 2048.5f), 0.0f, 4095.0f);
  return sigTab[(u32)f];
}

// Granule = 2 steps (p,q) x 2 rows (a,b) x 2 dst (u0,u1) = 8 sigmoids.
// x=1 split per step: a0 via LDS table; b0,b1 via trans (shared rcp within
// step); a1 via trans with rcp shared ACROSS p/q. All pairings use the
// proven r=rcp(P*P'); s=P'*r identity (inf only when both sigmoids ~0 ->
// rcp(inf)=0 -> exact 0).
__device__ __forceinline__ void granule(const Gr& g,
    float vap, float vbp, float vaq, float vbq,
    const float* __restrict__ sigTab,
    float& na0, float& da0, float& na1, float& da1,
    float& nb0, float& db0, float& nb1, float& db1) {
  u32 a0p = g.d[0], a1p = g.d[1], wp = g.d[2];
  u32 a0q = g.d[3], a1q = g.d[4], wq = g.d[5];
  u32 awp = wp & 0x7fff7fffu;        // |w| pairs (w*mask >= 0 pre-sign)
  u32 awq = wq & 0x7fff7fffu;
  // t values (v_fma_mix candidates)
  float tpa0 = fmaf(vap, lo2f(a0p), hi2f(a0p));
  float tpb0 = fmaf(vbp, lo2f(a0p), hi2f(a0p));
  float tpa1 = fmaf(vap, lo2f(a1p), hi2f(a1p));
  float tpb1 = fmaf(vbp, lo2f(a1p), hi2f(a1p));
  float tqa0 = fmaf(vaq, lo2f(a0q), hi2f(a0q));
  float tqb0 = fmaf(vbq, lo2f(a0q), hi2f(a0q));
  float tqa1 = fmaf(vaq, lo2f(a1q), hi2f(a1q));
  float tqb1 = fmaf(vbq, lo2f(a1q), hi2f(a1q));
  // table path: a0 of both steps (1 scattered LDS read per step)
  float spa0 = tab_sig(sigTab, tpa0);
  float sqa0 = tab_sig(sigTab, tqa0);
  // trans path: 6 exp + 3 rcp per granule
  float epb0 = __builtin_amdgcn_exp2f(tpb0);
  float epb1 = __builtin_amdgcn_exp2f(tpb1);
  float eqb0 = __builtin_amdgcn_exp2f(tqb0);
  float eqb1 = __builtin_amdgcn_exp2f(tqb1);
  float epa1 = __builtin_amdgcn_exp2f(tpa1);
  float eqa1 = __builtin_amdgcn_exp2f(tqa1);
  float Ppb0 = 1.f + epb0, Ppb1 = 1.f + epb1;
  float Pqb0 = 1.f + eqb0, Pqb1 = 1.f + eqb1;
  float Ppa1 = 1.f + epa1, Pqa1 = 1.f + eqa1;
  float rp = __builtin_amdgcn_rcpf(Ppb0 * Ppb1);
  float rq = __builtin_amdgcn_rcpf(Pqb0 * Pqb1);
  float ra = __builtin_amdgcn_rcpf(Ppa1 * Pqa1);
  float spb0 = Ppb1 * rp, spb1 = Ppb0 * rp;
  float sqb0 = Pqb1 * rq, sqb1 = Pqb0 * rq;
  float spa1 = Pqa1 * ra, sqa1 = Ppa1 * ra;
  // accumulate (fma_mix: f16 weight lo/hi, f32 acc)
  na0 = fmaf(spa0, lo2f(wp), na0);  da0 = fmaf(spa0, lo2f(awp), da0);
  na1 = fmaf(spa1, hi2f(wp), na1);  da1 = fmaf(spa1, hi2f(awp), da1);
  nb0 = fmaf(spb0, lo2f(wp), nb0);  db0 = fmaf(spb0, lo2f(awp), db0);
  nb1 = fmaf(spb1, hi2f(wp), nb1);  db1 = fmaf(spb1, hi2f(awp), db1);
  na0 = fmaf(sqa0, lo2f(wq), na0);  da0 = fmaf(sqa0, lo2f(awq), da0);
  na1 = fmaf(sqa1, hi2f(wq), na1);  da1 = fmaf(sqa1, hi2f(awq), da1);
  nb0 = fmaf(sqb0, lo2f(wq), nb0);  db0 = fmaf(sqb0, lo2f(awq), db0);
  nb1 = fmaf(sqb1, hi2f(wq), nb1);  db1 = fmaf(sqb1, hi2f(awq), db1);
}

// 32 granules = 64 j-steps. No explicit register buffers (R12 lesson:
// arrays spill); unroll-4 lets the compiler batch the b128/b64 loads.
__device__ __forceinline__ void run32(const Gr* __restrict__ pG, int baseG,
                                      float vsa, float vsb,
                                      const float* __restrict__ sigTab,
                                      float& na0, float& da0, float& na1, float& da1,
                                      float& nb0, float& db0, float& nb1, float& db1) {
  #pragma unroll 4
  for (int gi = 0; gi < 32; ++gi) {
    Gr rec = pG[(baseG + gi) * 64];
    float vap = rdlane(vsa, 2 * gi);
    float vaq = rdlane(vsa, 2 * gi + 1);
    float vbp = rdlane(vsb, 2 * gi);
    float vbq = rdlane(vsb, 2 * gi + 1);
    granule(rec, vap, vbp, vaq, vbq, sigTab,
            na0, da0, na1, da1, nb0, db0, nb1, db1);
  }
}

template<bool BF16>
__device__ __forceinline__ void body(
    const void* g_in, const void* g_state, const void* g_gleak, const void* g_vleak,
    const void* g_cm, const void* g_sigma, const void* g_mu, const void* g_w,
    const void* g_erev, const void* g_ssig, const void* g_smu, const void* g_sw,
    const void* g_serev, const void* g_mask, const void* g_smask,
    const void* g_iw, const void* g_ib, const void* g_ow, const void* g_ob,
    void* g_out,
    Gr* smG, float* sigTab)
{
  const int tid = threadIdx.x;           // 512 threads = 8 waves
  const int b0  = blockIdx.x * 16;       // 16 rows per block

  const int r  = tid >> 6;               // wave id, owns rows 2r, 2r+1
  const int u0 = tid & 63;
  const int u1 = u0 + 64;
  const int ba = b0 + 2 * r;
  const int bb = ba + 1;

  // ---- build sigmoid table (16 KB): s(t)=1/(1+2^t), t=(i-2048)/128 ----
  for (int i = tid; i < 4096; i += 512) {
    float t = (float)(i - 2048) * (1.0f / 128.0f);
    sigTab[i] = __builtin_amdgcn_rcpf(1.0f + __builtin_amdgcn_exp2f(t));
  }

  // ---- phase 1: stage sensory granules (32 granules x 64 lanes, 64 KB) ----
  #pragma unroll 2
  for (int e = tid; e < (NS / 2) * 64; e += 512) {
    int gi = e >> 6, l = e & 63;
    int sp = 2 * gi, sq = sp + 1;
    Gr rec;
    {
      int i0 = sp * NU + l, i1 = i0 + 64;
      float sl0 = LD<BF16>(g_ssig, i0) * LOG2E, sl1 = LD<BF16>(g_ssig, i1) * LOG2E;
      float ms0 = LD<BF16>(g_smu, i0) * sl0,    ms1 = LD<BF16>(g_smu, i1) * sl1;
      float w0 = LD<BF16>(g_sw, i0) * LD<BF16>(g_smask, i0) * LD<BF16>(g_serev, i0);
      float w1 = LD<BF16>(g_sw, i1) * LD<BF16>(g_smask, i1) * LD<BF16>(g_serev, i1);
      rec.d[0] = pk(-sl0, ms0); rec.d[1] = pk(-sl1, ms1); rec.d[2] = pk(w0, w1);
    }
    {
      int i0 = sq * NU + l, i1 = i0 + 64;
      float sl0 = LD<BF16>(g_ssig, i0) * LOG2E, sl1 = LD<BF16>(g_ssig, i1) * LOG2E;
      float ms0 = LD<BF16>(g_smu, i0) * sl0,    ms1 = LD<BF16>(g_smu, i1) * sl1;
      float w0 = LD<BF16>(g_sw, i0) * LD<BF16>(g_smask, i0) * LD<BF16>(g_serev, i0);
      float w1 = LD<BF16>(g_sw, i1) * LD<BF16>(g_smask, i1) * LD<BF16>(g_serev, i1);
      rec.d[3] = pk(-sl0, ms0); rec.d[4] = pk(-sl1, ms1); rec.d[5] = pk(w0, w1);
    }
    rec.pad[0] = 0u; rec.pad[1] = 0u;
    smG[e] = rec;
  }
  __syncthreads();   // table + sensory staged

  // per-lane x for both rows (lane doubles as sensory index s)
  float iw = LD<BF16>(g_iw, u0), ib = LD<BF16>(g_ib, u0);
  float xa = LD<BF16>(g_in, ba * NS + u0) * iw + ib;
  float xb = LD<BF16>(g_in, bb * NS + u0) * iw + ib;
  float va0 = LD<BF16>(g_state, ba * NU + u0);
  float va1 = LD<BF16>(g_state, ba * NU + u1);
  float vb0 = LD<BF16>(g_state, bb * NU + u0);
  float vb1 = LD<BF16>(g_state, bb * NU + u1);
  const float gl0 = LD<BF16>(g_gleak, u0), gl1 = LD<BF16>(g_gleak, u1);
  const float lk0 = gl0 * LD<BF16>(g_vleak, u0);
  const float lk1 = gl1 * LD<BF16>(g_vleak, u1);
  const float cm0 = LD<BF16>(g_cm, u0) * (float)UNFOLDS;
  const float cm1 = LD<BF16>(g_cm, u1) * (float)UNFOLDS;

  const Gr* pG = smG + u0;

  // ---- sensory accumulators (once per row-pair) ----
  float nsa0 = 0.f, dsa0 = 0.f, nsa1 = 0.f, dsa1 = 0.f;
  float nsb0 = 0.f, dsb0 = 0.f, nsb1 = 0.f, dsb1 = 0.f;
  run32(pG, 0, xa, xb, sigTab,
        nsa0, dsa0, nsa1, dsa1, nsb0, dsb0, nsb1, dsb1);
  __syncthreads();   // all waves done reading sensory area

  // ---- phase 2: stage recurrent granules (64 granules x 64 lanes, 128 KB) ----
  #pragma unroll 2
  for (int e = tid; e < (NU / 2) * 64; e += 512) {
    int gi = e >> 6, l = e & 63;
    int jp = 2 * gi, jq = jp + 1;
    Gr rec;
    {
      int i0 = jp * NU + l, i1 = i0 + 64;
      float sl0 = LD<BF16>(g_sigma, i0) * LOG2E, sl1 = LD<BF16>(g_sigma, i1) * LOG2E;
      float ms0 = LD<BF16>(g_mu, i0) * sl0,      ms1 = LD<BF16>(g_mu, i1) * sl1;
      float w0 = LD<BF16>(g_w, i0) * LD<BF16>(g_mask, i0) * LD<BF16>(g_erev, i0);
      float w1 = LD<BF16>(g_w, i1) * LD<BF16>(g_mask, i1) * LD<BF16>(g_erev, i1);
      rec.d[0] = pk(-sl0, ms0); rec.d[1] = pk(-sl1, ms1); rec.d[2] = pk(w0, w1);
    }
    {
      int i0 = jq * NU + l, i1 = i0 + 64;
      float sl0 = LD<BF16>(g_sigma, i0) * LOG2E, sl1 = LD<BF16>(g_sigma, i1) * LOG2E;
      float ms0 = LD<BF16>(g_mu, i0) * sl0,      ms1 = LD<BF16>(g_mu, i1) * sl1;
      float w0 = LD<BF16>(g_w, i0) * LD<BF16>(g_mask, i0) * LD<BF16>(g_erev, i0);
      float w1 = LD<BF16>(g_w, i1) * LD<BF16>(g_mask, i1) * LD<BF16>(g_erev, i1);
      rec.d[3] = pk(-sl0, ms0); rec.d[4] = pk(-sl1, ms1); rec.d[5] = pk(w0, w1);
    }
    rec.pad[0] = 0u; rec.pad[1] = 0u;
    smG[e] = rec;
  }
  __syncthreads();

  // ---- ODE unfolds: v in registers, broadcast via v_readlane; no barriers ----
  #pragma unroll 1
  for (int it = 0; it < UNFOLDS; ++it) {
    float na0 = nsa0, da0 = dsa0, na1 = nsa1, da1 = dsa1;
    float nb0 = nsb0, db0 = dsb0, nb1 = nsb1, db1 = dsb1;
    run32(pG, 0,  va0, vb0, sigTab,
          na0, da0, na1, da1, nb0, db0, nb1, db1);   // j 0..63
    run32(pG, 32, va1, vb1, sigTab,
          na0, da0, na1, da1, nb0, db0, nb1, db1);   // j 64..127
    va0 = fmaf(cm0, va0, lk0 + na0) * __builtin_amdgcn_rcpf(cm0 + gl0 + da0 + 1e-8f);
    va1 = fmaf(cm1, va1, lk1 + na1) * __builtin_amdgcn_rcpf(cm1 + gl1 + da1 + 1e-8f);
    vb0 = fmaf(cm0, vb0, lk0 + nb0) * __builtin_amdgcn_rcpf(cm0 + gl0 + db0 + 1e-8f);
    vb1 = fmaf(cm1, vb1, lk1 + nb1) * __builtin_amdgcn_rcpf(cm1 + gl1 + db1 + 1e-8f);
  }

  // ---- epilogue: out[B,M] then v[B,U], dtype matches input ----
  if (BF16) {
    u16* om = (u16*)g_out;
    u16* ov = om + B_TOTAL * NM;
    ov[ba * NU + u0] = f2bf(va0);
    ov[ba * NU + u1] = f2bf(va1);
    ov[bb * NU + u0] = f2bf(vb0);
    ov[bb * NU + u1] = f2bf(vb1);
    if (u0 < NM) {
      float ow = LD<true>(g_ow, u0), ob = LD<true>(g_ob, u0);
      om[ba * NM + u0] = f2bf(fmaf(va0, ow, ob));
      om[bb * NM + u0] = f2bf(fmaf(vb0, ow, ob));
    }
  } else {
    float* om = (float*)g_out;
    float* ov = om + B_TOTAL * NM;
    ov[ba * NU + u0] = va0;
    ov[ba * NU + u1] = va1;
    ov[bb * NU + u0] = vb0;
    ov[bb * NU + u1] = vb1;
    if (u0 < NM) {
      float ow = LD<false>(g_ow, u0), ob = LD<false>(g_ob, u0);
      om[ba * NM + u0] = fmaf(va0, ow, ob);
      om[bb * NM + u0] = fmaf(vb0, ow, ob);
    }
  }
}

__global__ __launch_bounds__(512, 2) void ltc_kernel(
    const void* g_in, const void* g_state, const void* g_gleak, const void* g_vleak,
    const void* g_cm, const void* g_sigma, const void* g_mu, const void* g_w,
    const void* g_erev, const void* g_ssig, const void* g_smu, const void* g_sw,
    const void* g_serev, const void* g_mask, const void* g_smask,
    const void* g_iw, const void* g_ib, const void* g_ow, const void* g_ob,
    void* g_out)
{
  // LDS: 128 KB granule records (overlaid sensory/recurrent) + 16 KB table
  __shared__ Gr    smG[(NU / 2) * 64];
  __shared__ float sigTab[4096];

  // runtime dtype probe: sigma in [3,8]; bf16 -> even u16s decode in-range
  const u16* sg = (const u16*)g_sigma;
  int cnt = 0;
  #pragma unroll
  for (int i = 0; i < 32; ++i) {
    float f = bf2f(sg[2 * i]);
    cnt += (f >= 2.0f && f <= 16.0f) ? 1 : 0;
  }
  if (cnt >= 24)
    body<true >(g_in, g_state, g_gleak, g_vleak, g_cm, g_sigma, g_mu, g_w, g_erev,
                g_ssig, g_smu, g_sw, g_serev, g_mask, g_smask,
                g_iw, g_ib, g_ow, g_ob, g_out, smG, sigTab);
  else
    body<false>(g_in, g_state, g_gleak, g_vleak, g_cm, g_sigma, g_mu, g_w, g_erev,
                g_ssig, g_smu, g_sw, g_serev, g_mask, g_smask,
                g_iw, g_ib, g_ow, g_ob, g_out, smG, sigTab);
}

extern "C" void kernel_launch(void* const* d_in, const int* in_sizes, int n_in,
                              void* d_out, int out_size, void* d_ws, size_t ws_size,
                              hipStream_t stream) {
  (void)in_sizes; (void)n_in; (void)out_size; (void)d_ws; (void)ws_size;
  dim3 grid(B_TOTAL / 16);   // 256 blocks = 1 per CU
  dim3 block(512);           // 8 waves x 2 rows = 16 rows
  hipLaunchKernelGGL(ltc_kernel, grid, block, 0, stream,
                     d_in[0], d_in[1], d_in[2], d_in[3], d_in[4],
                     d_in[5], d_in[6], d_in[7], d_in[8],
                     d_in[9], d_in[10], d_in[11], d_in[12],
                     d_in[13], d_in[14], d_in[15], d_in[16],
                     d_in[17], d_in[18], d_out);
}